// Round 11
// baseline (337.913 us; speedup 1.0000x reference)
//
#include <hip/hip_runtime.h>

#define LEAKY 0.2f

typedef __attribute__((ext_vector_type(8))) short short8;   // 8 bf16 (MFMA A/B frag)
typedef __attribute__((ext_vector_type(4))) float floatx4;  // MFMA C/D frag

__device__ __forceinline__ float bf2f(unsigned short u) {
    return __uint_as_float(((unsigned)u) << 16);
}
__device__ __forceinline__ unsigned short f2bf(float f) {
    unsigned u = __float_as_uint(f);
    unsigned r = (u + 0x7fffu + ((u >> 16) & 1u)) >> 16;  // RNE
    return (unsigned short)r;
}
__device__ __forceinline__ float relu_nan(float v) { return v < 0.0f ? 0.0f : v; }

// async global->LDS, 16 B per lane (dest = wave-uniform base + lane*16)
__device__ __forceinline__ void gload_lds16(const void* g, void* l) {
    __builtin_amdgcn_global_load_lds((const __attribute__((address_space(1))) void*)g,
                                     (__attribute__((address_space(3))) void*)l, 16, 0, 0);
}

// ---------- K_fill (ws-too-small diagnosis) ----------
__global__ void k_fill(float* __restrict__ p, float val, int n) {
    int i = blockIdx.x * blockDim.x + threadIdx.x;
    if (i < n) p[i] = val;
}

// ---------- K_prep: all elementwise prep fused (zero cnt/state, cvt X, 3 weight transposes) ----------
__global__ void k_prep(const float* __restrict__ X, unsigned short* __restrict__ Xb,
                       const float* __restrict__ Wn, unsigned short* __restrict__ WnT,
                       const float* __restrict__ W1, unsigned short* __restrict__ W1T,
                       const float* __restrict__ W2, unsigned short* __restrict__ W2T,
                       int* __restrict__ cnt, unsigned long long* __restrict__ state,
                       int N, int nstate) {
    const int gs = gridDim.x * blockDim.x;
    const int tid = blockIdx.x * blockDim.x + threadIdx.x;
    for (int i = tid; i < N; i += gs) cnt[i] = 0;
    for (int i = tid; i < nstate; i += gs) state[i] = 0ull;
    for (int i = tid; i < N * 32; i += gs) {
        float4 v = ((const float4*)X)[i];
        ushort4 o;
        o.x = f2bf(v.x); o.y = f2bf(v.y); o.z = f2bf(v.z); o.w = f2bf(v.w);
        ((ushort4*)Xb)[i] = o;
    }
    for (int i = tid; i < 256 * 128; i += gs) {   // WnT[col][k], col=head*64+d
        int col = i >> 7, k = i & 127;
        int head = col >> 6, d = col & 63;
        WnT[i] = f2bf(Wn[(size_t)head * 8192 + (size_t)k * 64 + d]);
    }
    for (int i = tid; i < 256 * 256; i += gs) {   // W1T[n][k] = W1[k][n]
        int n = i >> 8, k = i & 255;
        W1T[i] = f2bf(W1[(size_t)k * 256 + n]);
    }
    for (int i = tid; i < 128 * 256; i += gs) {   // W2T[n][k] = W2[k][n]
        int n = i >> 8, k = i & 255;
        W2T[i] = f2bf(W2[(size_t)k * 128 + n]);
    }
}

// ---------- K_hist ----------
__global__ void k_hist(const int* __restrict__ dst, int* __restrict__ cnt, int E) {
    int e = blockIdx.x * blockDim.x + threadIdx.x;
    if (e < E) atomicAdd(cnt + dst[e], 1);
}

// ---------- K_scan_lb: single-pass exclusive scan (decoupled lookback) ----------
// 196 blocks < 256 CUs -> all co-resident; agent-scope atomics for cross-XCD coherence.
__global__ __launch_bounds__(256) void k_scan_lb(
    const int* __restrict__ cnt, int* __restrict__ rowptr, int* __restrict__ wcnt,
    unsigned long long* __restrict__ state, int N, int E, int nblocks) {
    __shared__ int wtot[4];
    __shared__ int sprefix;
    const int lane = threadIdx.x & 63, wave = threadIdx.x >> 6;
    const int b = blockIdx.x;
    const int i = b * 256 + threadIdx.x;
    int v = (i < N) ? cnt[i] : 0;
    int x = v;
    for (int off = 1; off < 64; off <<= 1) {
        int y = __shfl_up(x, off, 64);
        if (lane >= off) x += y;
    }
    if (lane == 63) wtot[wave] = x;
    __syncthreads();
    int wo = 0;
    for (int wv = 0; wv < wave; ++wv) wo += wtot[wv];
    const int excl = wo + x - v;
    if (threadIdx.x == 0) {
        const int tot = wtot[0] + wtot[1] + wtot[2] + wtot[3];
        // publish aggregate (flag bit0)
        __hip_atomic_store(&state[b], (((unsigned long long)(unsigned)tot) << 2) | 1ull,
                           __ATOMIC_RELEASE, __HIP_MEMORY_SCOPE_AGENT);
        unsigned long long run = 0;
        for (int j = b - 1; j >= 0; --j) {
            unsigned long long s;
            do {
                s = __hip_atomic_load(&state[j], __ATOMIC_ACQUIRE, __HIP_MEMORY_SCOPE_AGENT);
            } while ((s & 3ull) == 0);
            run += s >> 2;
            if (s & 2ull) break;   // j published inclusive prefix: done
        }
        const int prefix = (int)run;
        __hip_atomic_store(&state[b], (((unsigned long long)(unsigned)(prefix + tot)) << 2) | 3ull,
                           __ATOMIC_RELEASE, __HIP_MEMORY_SCOPE_AGENT);
        sprefix = prefix;
    }
    __syncthreads();
    const int p = sprefix;
    if (i < N) { rowptr[i] = p + excl; wcnt[i] = p + excl; }
    if (b == nblocks - 1 && threadIdx.x == 255) rowptr[N] = E;
}

// ---------- K_scatter: src ids into CSR order ----------
__global__ void k_scatter(const int* __restrict__ src, const int* __restrict__ dst,
                          int* __restrict__ wcnt, int* __restrict__ esrc, int E) {
    int e = blockIdx.x * blockDim.x + threadIdx.x;
    if (e < E) {
        int pos = atomicAdd(wcnt + dst[e], 1);
        esrc[pos] = src[e];
    }
}

// ---------- K_agg: per-dst gather-aggregate -> concat (bf16, into d_out); zero LDS ----------
__global__ __launch_bounds__(256) void k_agg(
    const float* __restrict__ s_src, const float* __restrict__ s_dst,
    const unsigned short* __restrict__ h_bf,
    const int* __restrict__ rowptr, const int* __restrict__ esrc,
    unsigned short* __restrict__ concat) {
    const int t = threadIdx.x;
    const int lane = t & 63;
    const int wave = t >> 6;
    const int row0 = blockIdx.x * 16;
    const int head = lane >> 4;
    const int c0 = lane << 2;
    const int eslot = lane & 15;
    const int hsel = lane & 48;

    for (int rr = 0; rr < 4; ++rr) {
        const int n = row0 + wave * 4 + rr;
        const int beg = rowptr[n], end = rowptr[n + 1];
        const float sdst = s_dst[n * 4 + head];
        float num0 = 0, num1 = 0, num2 = 0, num3 = 0, den = 0;
        for (int base = beg; base < end; base += 16) {
            const int nn = end - base;
            int sid = 0;
            float my_ex = 0.0f;
            if (eslot < nn) {
                sid = esrc[base + eslot];
                float v = s_src[sid * 4 + head] + sdst;
                v = v > 0.0f ? v : LEAKY * v;
                my_ex = __expf(v);
            }
#pragma unroll
            for (int e = 0; e < 16; ++e) {
                float ex = __shfl(my_ex, hsel | e, 64);
                int s    = __shfl(sid, e, 64);
                ushort4 hv = *(const ushort4*)(h_bf + (size_t)s * 256 + c0);
                num0 += ex * bf2f(hv.x);
                num1 += ex * bf2f(hv.y);
                num2 += ex * bf2f(hv.z);
                num3 += ex * bf2f(hv.w);
                den  += ex;
            }
        }
        const float inv = 1.0f / (den > 0.0f ? den : 1.0f);
        ushort4 o;
        o.x = f2bf(relu_nan(num0 * inv));
        o.y = f2bf(relu_nan(num1 * inv));
        o.z = f2bf(relu_nan(num2 * inv));
        o.w = f2bf(relu_nan(num3 * inv));
        *(ushort4*)(concat + (size_t)n * 256 + c0) = o;
    }
}

// ---------- K_gemm: tiled MFMA GEMM, templated on K and epilogue ----------
// MODE 0: bf16 out, no bias, no relu; FUSED score epilogue (each wave owns one head's 64 cols)
// MODE 1: bf16 out, +bias, relu     (MLP layer 1 -> hidden)
// MODE 2: fp32 out, +bias           (MLP layer 2 -> final)
template <int K, int MODE>
__global__ __launch_bounds__(256) void k_gemm(
    const unsigned short* __restrict__ A, const unsigned short* __restrict__ BT,
    const float* __restrict__ bias, unsigned short* __restrict__ Cb,
    float* __restrict__ Cf, int N, int ldout,
    const float* __restrict__ asrc, const float* __restrict__ adst,
    float* __restrict__ s_src, float* __restrict__ s_dst) {
    __shared__ unsigned short As[128 * 32];
    __shared__ unsigned short Bs[128 * 32];
    const int t = threadIdx.x;
    const int lane = t & 63;
    const int w = t >> 6;
    const int wy = w >> 1, wx = w & 1;
    const int lm = lane & 15, quad = lane >> 4;
    const int row0 = blockIdx.x * 128;
    const int n0 = blockIdx.y * 128;
    const int srow = lane >> 2;
    const int sk = (lane & 3) * 8;

    floatx4 acc[4][4];
    if (MODE == 0) {
#pragma unroll
        for (int mi = 0; mi < 4; ++mi)
#pragma unroll
            for (int ni = 0; ni < 4; ++ni) acc[mi][ni] = (floatx4){0, 0, 0, 0};
    } else {
#pragma unroll
        for (int ni = 0; ni < 4; ++ni) {
            float b = bias[n0 + wx * 64 + ni * 16 + lm];
#pragma unroll
            for (int mi = 0; mi < 4; ++mi) acc[mi][ni] = (floatx4){b, b, b, b};
        }
    }

    for (int k0 = 0; k0 < K; k0 += 32) {
#pragma unroll
        for (int p = 0; p < 2; ++p) {
            int tr = (p * 4 + w) * 16 + srow;
            int ga = row0 + tr; if (ga >= N) ga = N - 1;   // clamp (stores guarded)
            gload_lds16(A + (size_t)ga * K + k0 + sk,
                        (char*)As + (size_t)tr * 64 + sk * 2);
            gload_lds16(BT + (size_t)(n0 + tr) * K + k0 + sk,
                        (char*)Bs + (size_t)tr * 64 + sk * 2);
        }
        __syncthreads();
        short8 af[4], bfr[4];
#pragma unroll
        for (int mi = 0; mi < 4; ++mi)
            af[mi] = *(const short8*)(As + (size_t)(wy * 64 + mi * 16 + lm) * 32 + quad * 8);
#pragma unroll
        for (int ni = 0; ni < 4; ++ni)
            bfr[ni] = *(const short8*)(Bs + (size_t)(wx * 64 + ni * 16 + lm) * 32 + quad * 8);
#pragma unroll
        for (int mi = 0; mi < 4; ++mi)
#pragma unroll
            for (int ni = 0; ni < 4; ++ni)
                acc[mi][ni] = __builtin_amdgcn_mfma_f32_16x16x32_bf16(af[mi], bfr[ni], acc[mi][ni], 0, 0, 0);
        __syncthreads();
    }

#pragma unroll
    for (int mi = 0; mi < 4; ++mi)
#pragma unroll
        for (int ni = 0; ni < 4; ++ni)
#pragma unroll
            for (int q = 0; q < 4; ++q) {
                int r = row0 + wy * 64 + mi * 16 + quad * 4 + q;
                int c = n0 + wx * 64 + ni * 16 + lm;
                if (r < N) {
                    if (MODE == 0)      Cb[(size_t)r * ldout + c] = f2bf(acc[mi][ni][q]);
                    else if (MODE == 1) Cb[(size_t)r * ldout + c] = f2bf(relu_nan(acc[mi][ni][q]));
                    else                Cf[(size_t)r * ldout + c] = acc[mi][ni][q];
                }
            }

    if (MODE == 0) {
        // fused attention-score epilogue: this wave's 64 cols = one full head
        const int head = blockIdx.y * 2 + wx;
        float as[4], ad[4];
#pragma unroll
        for (int ni = 0; ni < 4; ++ni) {
            int d = ni * 16 + lm;
            as[ni] = asrc[head * 64 + d];
            ad[ni] = adst[head * 64 + d];
        }
#pragma unroll
        for (int mi = 0; mi < 4; ++mi)
#pragma unroll
            for (int q = 0; q < 4; ++q) {
                float ps = acc[mi][0][q] * as[0] + acc[mi][1][q] * as[1]
                         + acc[mi][2][q] * as[2] + acc[mi][3][q] * as[3];
                float pd = acc[mi][0][q] * ad[0] + acc[mi][1][q] * ad[1]
                         + acc[mi][2][q] * ad[2] + acc[mi][3][q] * ad[3];
#pragma unroll
                for (int m = 1; m < 16; m <<= 1) {
                    ps += __shfl_xor(ps, m, 64);
                    pd += __shfl_xor(pd, m, 64);
                }
                if (lm == 0) {
                    int r = row0 + wy * 64 + mi * 16 + quad * 4 + q;
                    if (r < N) {
                        s_src[r * 4 + head] = ps;
                        s_dst[r * 4 + head] = pd;
                    }
                }
            }
    }
}

extern "C" void kernel_launch(void* const* d_in, const int* in_sizes, int n_in,
                              void* d_out, int out_size, void* d_ws, size_t ws_size,
                              hipStream_t stream) {
    const float* X    = (const float*)d_in[0];
    const int* src    = (const int*)d_in[1];
    const int* dst    = (const int*)d_in[2];
    const float* Wn   = (const float*)d_in[3];
    const float* Asrc = (const float*)d_in[4];
    const float* Adst = (const float*)d_in[5];
    const float* W1   = (const float*)d_in[6];
    const float* b1   = (const float*)d_in[7];
    const float* W2   = (const float*)d_in[8];
    const float* b2   = (const float*)d_in[9];
    float* out = (float*)d_out;

    const int N = in_sizes[0] / 128;   // 50000
    const int E = in_sizes[1];         // 800000
    const int NBS = (N + 255) / 256;   // scan blocks (196)
    const int NR = (N + 127) / 128;    // GEMM row tiles

    // ws layout (16B-aligned offsets), ~31.3 MB.
    // h_bf doubles as the MLP hidden buffer after k_agg consumes it.
    size_t off = 0;
    char* w = (char*)d_ws;
    unsigned short* h_bf = (unsigned short*)(w + off); off += (size_t)N * 256 * 2;
    float* s_src = (float*)(w + off);                  off += (size_t)N * 4 * 4;
    float* s_dst = (float*)(w + off);                  off += (size_t)N * 4 * 4;
    int* cnt     = (int*)(w + off);                    off += (size_t)N * 4;
    int* rowptr  = (int*)(w + off);                    off += ((size_t)(N + 1) * 4 + 15) & ~15ull;
    int* wcnt    = (int*)(w + off);                    off += (size_t)N * 4;
    unsigned long long* state = (unsigned long long*)(w + off); off += (size_t)NBS * 8;
    int* esrc    = (int*)(w + off);                    off += (size_t)E * 4;
    unsigned short* W1T = (unsigned short*)(w + off);  off += 256 * 256 * 2;
    unsigned short* W2T = (unsigned short*)(w + off);  off += 128 * 256 * 2;
    unsigned short* WnT = (unsigned short*)(w + off);  off += 256 * 128 * 2;
    const size_t required = off;

    if (ws_size < required) {
        k_fill<<<dim3((out_size + 255) / 256), dim3(256), 0, stream>>>(
            out, (float)(ws_size >> 20), out_size);
        return;
    }

    // d_out staging: Xb (bf16 [N,128]) -> consumed by transform GEMM;
    // then concat (bf16 [N,256]) -> consumed by gemm1; then final fp32 out.
    unsigned short* Xb     = (unsigned short*)d_out;
    unsigned short* concat = (unsigned short*)d_out;

    k_prep<<<dim3(2048), dim3(256), 0, stream>>>(X, Xb, Wn, WnT, W1, W1T, W2, W2T,
                                                 cnt, state, N, NBS);
    // h = Xb @ WnT (MFMA) + fused s_src/s_dst epilogue
    k_gemm<128, 0><<<dim3(NR, 2), dim3(256), 0, stream>>>(
        Xb, WnT, nullptr, h_bf, nullptr, N, 256, Asrc, Adst, s_src, s_dst);
    k_hist<<<dim3((E + 255) / 256), dim3(256), 0, stream>>>(dst, cnt, E);
    k_scan_lb<<<dim3(NBS), dim3(256), 0, stream>>>(cnt, rowptr, wcnt, state, N, E, NBS);
    k_scatter<<<dim3((E + 255) / 256), dim3(256), 0, stream>>>(src, dst, wcnt, esrc, E);
    k_agg<<<dim3(N / 16), dim3(256), 0, stream>>>(s_src, s_dst, h_bf, rowptr, esrc, concat);
    // layer 1: hidden = relu(concat @ W1 + b1) -> h_bf (h is dead after k_agg)
    k_gemm<256, 1><<<dim3(NR, 2), dim3(256), 0, stream>>>(
        concat, W1T, b1, h_bf, nullptr, N, 256, nullptr, nullptr, nullptr, nullptr);
    // layer 2: out = hidden @ W2 + b2 -> fp32 into d_out
    k_gemm<256, 2><<<dim3(NR, 1), dim3(256), 0, stream>>>(
        h_bf, W2T, b2, nullptr, out, N, 128, nullptr, nullptr, nullptr, nullptr);
}

// Round 12
// 312.292 us; speedup vs baseline: 1.0820x; 1.0820x over previous
//
#include <hip/hip_runtime.h>

#define LEAKY 0.2f

typedef __attribute__((ext_vector_type(8))) short short8;   // 8 bf16 (MFMA A/B frag)
typedef __attribute__((ext_vector_type(4))) float floatx4;  // MFMA C/D frag

__device__ __forceinline__ float bf2f(unsigned short u) {
    return __uint_as_float(((unsigned)u) << 16);
}
__device__ __forceinline__ unsigned short f2bf(float f) {
    unsigned u = __float_as_uint(f);
    unsigned r = (u + 0x7fffu + ((u >> 16) & 1u)) >> 16;  // RNE
    return (unsigned short)r;
}
__device__ __forceinline__ float relu_nan(float v) { return v < 0.0f ? 0.0f : v; }

// async global->LDS, 16 B per lane (dest = wave-uniform base + lane*16)
__device__ __forceinline__ void gload_lds16(const void* g, void* l) {
    __builtin_amdgcn_global_load_lds((const __attribute__((address_space(1))) void*)g,
                                     (__attribute__((address_space(3))) void*)l, 16, 0, 0);
}

// ---------- K_fill (ws-too-small diagnosis) ----------
__global__ void k_fill(float* __restrict__ p, float val, int n) {
    int i = blockIdx.x * blockDim.x + threadIdx.x;
    if (i < n) p[i] = val;
}

// ---------- K_prep: fused elementwise prep (zero cnt, cvt X, 3 weight transposes) ----------
__global__ void k_prep(const float* __restrict__ X, unsigned short* __restrict__ Xb,
                       const float* __restrict__ Wn, unsigned short* __restrict__ WnT,
                       const float* __restrict__ W1, unsigned short* __restrict__ W1T,
                       const float* __restrict__ W2, unsigned short* __restrict__ W2T,
                       int* __restrict__ cnt, int N) {
    const int gs = gridDim.x * blockDim.x;
    const int tid = blockIdx.x * blockDim.x + threadIdx.x;
    for (int i = tid; i < N; i += gs) cnt[i] = 0;
    for (int i = tid; i < N * 32; i += gs) {
        float4 v = ((const float4*)X)[i];
        ushort4 o;
        o.x = f2bf(v.x); o.y = f2bf(v.y); o.z = f2bf(v.z); o.w = f2bf(v.w);
        ((ushort4*)Xb)[i] = o;
    }
    for (int i = tid; i < 256 * 128; i += gs) {   // WnT[col][k], col=head*64+d
        int col = i >> 7, k = i & 127;
        int head = col >> 6, d = col & 63;
        WnT[i] = f2bf(Wn[(size_t)head * 8192 + (size_t)k * 64 + d]);
    }
    for (int i = tid; i < 256 * 256; i += gs) {   // W1T[n][k] = W1[k][n]
        int n = i >> 8, k = i & 255;
        W1T[i] = f2bf(W1[(size_t)k * 256 + n]);
    }
    for (int i = tid; i < 128 * 256; i += gs) {   // W2T[n][k] = W2[k][n]
        int n = i >> 8, k = i & 255;
        W2T[i] = f2bf(W2[(size_t)k * 128 + n]);
    }
}

// ---------- K_hist ----------
__global__ void k_hist(const int* __restrict__ dst, int* __restrict__ cnt, int E) {
    int e = blockIdx.x * blockDim.x + threadIdx.x;
    if (e < E) atomicAdd(cnt + dst[e], 1);
}

// ---------- K3a/b/c: two-level exclusive scan (proven R6-R10 version) ----------
__global__ __launch_bounds__(256) void k_scan1(
    const int* __restrict__ cnt, int* __restrict__ rowptr, int* __restrict__ bsum, int N) {
    __shared__ int wtot[4];
    const int lane = threadIdx.x & 63, wave = threadIdx.x >> 6;
    const int i = blockIdx.x * 256 + threadIdx.x;
    int v = (i < N) ? cnt[i] : 0;
    int x = v;
    for (int off = 1; off < 64; off <<= 1) {
        int y = __shfl_up(x, off, 64);
        if (lane >= off) x += y;
    }
    if (lane == 63) wtot[wave] = x;
    __syncthreads();
    int wo = 0;
    for (int wv = 0; wv < wave; ++wv) wo += wtot[wv];
    if (i < N) rowptr[i] = wo + x - v;
    if (threadIdx.x == 255) bsum[blockIdx.x] = wo + x;
}
__global__ void k_scan2(int* __restrict__ bsum, int nb) {
    const int lane = threadIdx.x;
    int carry = 0;
    for (int base = 0; base < nb; base += 64) {
        int i = base + lane;
        int v = (i < nb) ? bsum[i] : 0;
        int x = v;
        for (int off = 1; off < 64; off <<= 1) {
            int y = __shfl_up(x, off, 64);
            if (lane >= off) x += y;
        }
        if (i < nb) bsum[i] = carry + x - v;
        carry += __shfl(x, 63, 64);
    }
}
__global__ void k_scan3(int* __restrict__ rowptr, const int* __restrict__ bsum,
                        int* __restrict__ wcnt, int N, int E) {
    int i = blockIdx.x * blockDim.x + threadIdx.x;
    if (i < N) {
        int v = rowptr[i] + bsum[i >> 8];
        rowptr[i] = v;
        wcnt[i] = v;
    }
    if (i == N) rowptr[N] = E;
}

// ---------- K_scatter: src ids into CSR order ----------
__global__ void k_scatter(const int* __restrict__ src, const int* __restrict__ dst,
                          int* __restrict__ wcnt, int* __restrict__ esrc, int E) {
    int e = blockIdx.x * blockDim.x + threadIdx.x;
    if (e < E) {
        int pos = atomicAdd(wcnt + dst[e], 1);
        esrc[pos] = src[e];
    }
}

// ---------- K_agg: per-dst gather-aggregate -> concat (bf16, into d_out); zero LDS ----------
__global__ __launch_bounds__(256) void k_agg(
    const float* __restrict__ s_src, const float* __restrict__ s_dst,
    const unsigned short* __restrict__ h_bf,
    const int* __restrict__ rowptr, const int* __restrict__ esrc,
    unsigned short* __restrict__ concat) {
    const int t = threadIdx.x;
    const int lane = t & 63;
    const int wave = t >> 6;
    const int row0 = blockIdx.x * 16;
    const int head = lane >> 4;
    const int c0 = lane << 2;
    const int eslot = lane & 15;
    const int hsel = lane & 48;

    for (int rr = 0; rr < 4; ++rr) {
        const int n = row0 + wave * 4 + rr;
        const int beg = rowptr[n], end = rowptr[n + 1];
        const float sdst = s_dst[n * 4 + head];
        float num0 = 0, num1 = 0, num2 = 0, num3 = 0, den = 0;
        for (int base = beg; base < end; base += 16) {
            const int nn = end - base;
            int sid = 0;
            float my_ex = 0.0f;
            if (eslot < nn) {
                sid = esrc[base + eslot];
                float v = s_src[sid * 4 + head] + sdst;
                v = v > 0.0f ? v : LEAKY * v;
                my_ex = __expf(v);
            }
#pragma unroll
            for (int e = 0; e < 16; ++e) {
                float ex = __shfl(my_ex, hsel | e, 64);
                int s    = __shfl(sid, e, 64);
                ushort4 hv = *(const ushort4*)(h_bf + (size_t)s * 256 + c0);
                num0 += ex * bf2f(hv.x);
                num1 += ex * bf2f(hv.y);
                num2 += ex * bf2f(hv.z);
                num3 += ex * bf2f(hv.w);
                den  += ex;
            }
        }
        const float inv = 1.0f / (den > 0.0f ? den : 1.0f);
        ushort4 o;
        o.x = f2bf(relu_nan(num0 * inv));
        o.y = f2bf(relu_nan(num1 * inv));
        o.z = f2bf(relu_nan(num2 * inv));
        o.w = f2bf(relu_nan(num3 * inv));
        *(ushort4*)(concat + (size_t)n * 256 + c0) = o;
    }
}

// ---------- K_gemm: tiled MFMA GEMM, templated on K and epilogue ----------
// MODE 0: bf16 out, no bias/relu; FUSED score epilogue (each wave owns one head's 64 cols)
// MODE 1: bf16 out, +bias, relu     (MLP layer 1 -> hidden)
// MODE 2: fp32 out, +bias           (MLP layer 2 -> final)
template <int K, int MODE>
__global__ __launch_bounds__(256) void k_gemm(
    const unsigned short* __restrict__ A, const unsigned short* __restrict__ BT,
    const float* __restrict__ bias, unsigned short* __restrict__ Cb,
    float* __restrict__ Cf, int N, int ldout,
    const float* __restrict__ asrc, const float* __restrict__ adst,
    float* __restrict__ s_src, float* __restrict__ s_dst) {
    __shared__ unsigned short As[128 * 32];
    __shared__ unsigned short Bs[128 * 32];
    const int t = threadIdx.x;
    const int lane = t & 63;
    const int w = t >> 6;
    const int wy = w >> 1, wx = w & 1;
    const int lm = lane & 15, quad = lane >> 4;
    const int row0 = blockIdx.x * 128;
    const int n0 = blockIdx.y * 128;
    const int srow = lane >> 2;
    const int sk = (lane & 3) * 8;

    floatx4 acc[4][4];
    if (MODE == 0) {
#pragma unroll
        for (int mi = 0; mi < 4; ++mi)
#pragma unroll
            for (int ni = 0; ni < 4; ++ni) acc[mi][ni] = (floatx4){0, 0, 0, 0};
    } else {
#pragma unroll
        for (int ni = 0; ni < 4; ++ni) {
            float b = bias[n0 + wx * 64 + ni * 16 + lm];
#pragma unroll
            for (int mi = 0; mi < 4; ++mi) acc[mi][ni] = (floatx4){b, b, b, b};
        }
    }

    for (int k0 = 0; k0 < K; k0 += 32) {
#pragma unroll
        for (int p = 0; p < 2; ++p) {
            int tr = (p * 4 + w) * 16 + srow;
            int ga = row0 + tr; if (ga >= N) ga = N - 1;   // clamp (stores guarded)
            gload_lds16(A + (size_t)ga * K + k0 + sk,
                        (char*)As + (size_t)tr * 64 + sk * 2);
            gload_lds16(BT + (size_t)(n0 + tr) * K + k0 + sk,
                        (char*)Bs + (size_t)tr * 64 + sk * 2);
        }
        __syncthreads();
        short8 af[4], bfr[4];
#pragma unroll
        for (int mi = 0; mi < 4; ++mi)
            af[mi] = *(const short8*)(As + (size_t)(wy * 64 + mi * 16 + lm) * 32 + quad * 8);
#pragma unroll
        for (int ni = 0; ni < 4; ++ni)
            bfr[ni] = *(const short8*)(Bs + (size_t)(wx * 64 + ni * 16 + lm) * 32 + quad * 8);
#pragma unroll
        for (int mi = 0; mi < 4; ++mi)
#pragma unroll
            for (int ni = 0; ni < 4; ++ni)
                acc[mi][ni] = __builtin_amdgcn_mfma_f32_16x16x32_bf16(af[mi], bfr[ni], acc[mi][ni], 0, 0, 0);
        __syncthreads();
    }

#pragma unroll
    for (int mi = 0; mi < 4; ++mi)
#pragma unroll
        for (int ni = 0; ni < 4; ++ni)
#pragma unroll
            for (int q = 0; q < 4; ++q) {
                int r = row0 + wy * 64 + mi * 16 + quad * 4 + q;
                int c = n0 + wx * 64 + ni * 16 + lm;
                if (r < N) {
                    if (MODE == 0)      Cb[(size_t)r * ldout + c] = f2bf(acc[mi][ni][q]);
                    else if (MODE == 1) Cb[(size_t)r * ldout + c] = f2bf(relu_nan(acc[mi][ni][q]));
                    else                Cf[(size_t)r * ldout + c] = acc[mi][ni][q];
                }
            }

    if (MODE == 0) {
        // fused attention-score epilogue: this wave's 64 cols = one full head
        const int head = blockIdx.y * 2 + wx;
        float as[4], ad[4];
#pragma unroll
        for (int ni = 0; ni < 4; ++ni) {
            int d = ni * 16 + lm;
            as[ni] = asrc[head * 64 + d];
            ad[ni] = adst[head * 64 + d];
        }
#pragma unroll
        for (int mi = 0; mi < 4; ++mi)
#pragma unroll
            for (int q = 0; q < 4; ++q) {
                float ps = acc[mi][0][q] * as[0] + acc[mi][1][q] * as[1]
                         + acc[mi][2][q] * as[2] + acc[mi][3][q] * as[3];
                float pd = acc[mi][0][q] * ad[0] + acc[mi][1][q] * ad[1]
                         + acc[mi][2][q] * ad[2] + acc[mi][3][q] * ad[3];
#pragma unroll
                for (int m = 1; m < 16; m <<= 1) {
                    ps += __shfl_xor(ps, m, 64);
                    pd += __shfl_xor(pd, m, 64);
                }
                if (lm == 0) {
                    int r = row0 + wy * 64 + mi * 16 + quad * 4 + q;
                    if (r < N) {
                        s_src[r * 4 + head] = ps;
                        s_dst[r * 4 + head] = pd;
                    }
                }
            }
    }
}

extern "C" void kernel_launch(void* const* d_in, const int* in_sizes, int n_in,
                              void* d_out, int out_size, void* d_ws, size_t ws_size,
                              hipStream_t stream) {
    const float* X    = (const float*)d_in[0];
    const int* src    = (const int*)d_in[1];
    const int* dst    = (const int*)d_in[2];
    const float* Wn   = (const float*)d_in[3];
    const float* Asrc = (const float*)d_in[4];
    const float* Adst = (const float*)d_in[5];
    const float* W1   = (const float*)d_in[6];
    const float* b1   = (const float*)d_in[7];
    const float* W2   = (const float*)d_in[8];
    const float* b2   = (const float*)d_in[9];
    float* out = (float*)d_out;

    const int N = in_sizes[0] / 128;   // 50000
    const int E = in_sizes[1];         // 800000
    const int NBS = (N + 255) / 256;   // scan blocks
    const int NR = (N + 127) / 128;    // GEMM row tiles

    // ws layout (16B-aligned offsets), ~31.3 MB.
    size_t off = 0;
    char* w = (char*)d_ws;
    unsigned short* h_bf = (unsigned short*)(w + off); off += (size_t)N * 256 * 2;
    float* s_src = (float*)(w + off);                  off += (size_t)N * 4 * 4;
    float* s_dst = (float*)(w + off);                  off += (size_t)N * 4 * 4;
    int* cnt     = (int*)(w + off);                    off += (size_t)N * 4;
    int* rowptr  = (int*)(w + off);                    off += ((size_t)(N + 1) * 4 + 15) & ~15ull;
    int* wcnt    = (int*)(w + off);                    off += (size_t)N * 4;
    int* bsum    = (int*)(w + off);                    off += ((size_t)NBS * 4 + 15) & ~15ull;
    int* esrc    = (int*)(w + off);                    off += (size_t)E * 4;
    unsigned short* W1T = (unsigned short*)(w + off);  off += 256 * 256 * 2;
    unsigned short* W2T = (unsigned short*)(w + off);  off += 128 * 256 * 2;
    unsigned short* WnT = (unsigned short*)(w + off);  off += 256 * 128 * 2;
    const size_t required = off;

    if (ws_size < required) {
        k_fill<<<dim3((out_size + 255) / 256), dim3(256), 0, stream>>>(
            out, (float)(ws_size >> 20), out_size);
        return;
    }

    // d_out staging: Xb (bf16 [N,128]) -> consumed by transform GEMM;
    // then concat (bf16 [N,256]) -> consumed by gemm1; then final fp32 out.
    unsigned short* Xb     = (unsigned short*)d_out;
    unsigned short* concat = (unsigned short*)d_out;

    k_prep<<<dim3(2048), dim3(256), 0, stream>>>(X, Xb, Wn, WnT, W1, W1T, W2, W2T, cnt, N);
    // h = Xb @ WnT (MFMA) + fused s_src/s_dst epilogue
    k_gemm<128, 0><<<dim3(NR, 2), dim3(256), 0, stream>>>(
        Xb, WnT, nullptr, h_bf, nullptr, N, 256, Asrc, Adst, s_src, s_dst);
    k_hist<<<dim3((E + 255) / 256), dim3(256), 0, stream>>>(dst, cnt, E);
    k_scan1<<<dim3(NBS), dim3(256), 0, stream>>>(cnt, rowptr, bsum, N);
    k_scan2<<<dim3(1), dim3(64), 0, stream>>>(bsum, NBS);
    k_scan3<<<dim3((N + 256) / 256), dim3(256), 0, stream>>>(rowptr, bsum, wcnt, N, E);
    k_scatter<<<dim3((E + 255) / 256), dim3(256), 0, stream>>>(src, dst, wcnt, esrc, E);
    k_agg<<<dim3(N / 16), dim3(256), 0, stream>>>(s_src, s_dst, h_bf, rowptr, esrc, concat);
    // layer 1: hidden = relu(concat @ W1 + b1) -> h_bf (h is dead after k_agg)
    k_gemm<256, 1><<<dim3(NR, 2), dim3(256), 0, stream>>>(
        concat, W1T, b1, h_bf, nullptr, N, 256, nullptr, nullptr, nullptr, nullptr);
    // layer 2: out = hidden @ W2 + b2 -> fp32 into d_out
    k_gemm<256, 2><<<dim3(NR, 1), dim3(256), 0, stream>>>(
        h_bf, W2T, b2, nullptr, out, N, 128, nullptr, nullptr, nullptr, nullptr);
}